// Round 1
// baseline (33.061 us; speedup 1.0000x reference)
//
#include <hip/hip_runtime.h>
#include <math.h>

#define NB 32
#define NA 5
#define NC 13
#define NHH 76
#define NWW 76
#define NT 50
#define CH (19 + NC)          // 32 channels per anchor
#define CELLS (NHH * NWW)     // 5776
#define TOTAL (NB * NA * CELLS) // 924160
#define MAIN_BLOCKS (TOTAL / 256) // 3610 exactly

#define COORD_SCALE 1.0f
#define OBJ_SCALE 5.0f
#define TH_ 80.0f
#define SHARP_ 2.0f
#define IMW_ 640.0f
#define IMH_ 480.0f

// ws layout (bytes):
//   [0)            cellmap : int32  NB*CELLS          = 739328 B
//   [739328)       conf_t  : float  NB*NT             = 6400 B
//   [745728)       tvals   : float  NB*NT*18          = 115200 B
//   [860928)       partials: double MAIN_BLOCKS       = 28880 B
#define WS_CONF_T_OFF 739328
#define WS_TVALS_OFF  745728
#define WS_PART_OFF   860928

__device__ __forceinline__ float sigmoidf_(float x) {
    return 1.0f / (1.0f + expf(-x));
}

// One block per batch; threads 0..49 handle targets.
__global__ void targets_kernel(const float* __restrict__ outp,
                               const float* __restrict__ tgt,
                               int* __restrict__ cellmap,
                               float* __restrict__ conf_t_ws,
                               float* __restrict__ tvals_ws) {
    int b = blockIdx.x;
    int t = threadIdx.x;
    __shared__ int sgi[NT], sgj[NT], snz[NT], svalid[NT];

    if (t < NT) {
        const float* tg = tgt + (size_t)(b * NT + t) * 21;
        float cx = tg[1];
        float cy = tg[2];
        sgi[t] = (int)floorf(cx * (float)NWW);
        sgj[t] = (int)floorf(cy * (float)NHH);
        snz[t] = (cx != 0.0f) ? 1 : 0;
    }
    __syncthreads();
    if (t < NT) {
        int v = 1;
        for (int k = 0; k <= t; ++k) v &= snz[k];  // cumprod of (x != 0)
        svalid[t] = v;
    }
    __syncthreads();

    if (t < NT) {
        const float* tg = tgt + (size_t)(b * NT + t) * 21;
        int gi = sgi[t], gj = sgj[t];
        int gic = min(max(gi, 0), NWW - 1);  // gather clips OOB
        int gjc = min(max(gj, 0), NHH - 1);

        // conf_t: distance between target coords and anchor-0 predicted box at (gjc,gic)
        const float* ob = outp + (size_t)(b * NA) * CH * CELLS + (size_t)gjc * NWW + gic;
        float ssum = 0.0f;
        const float denom = expf(SHARP_) - 1.0f + 1e-5f;
        for (int k = 0; k < 9; ++k) {
            float vx = ob[(size_t)(2 * k) * CELLS];
            float vy = ob[(size_t)(2 * k + 1) * CELLS];
            if (k == 0) { vx = sigmoidf_(vx); vy = sigmoidf_(vy); }  // only channels 0,1 sigmoided
            float px = (vx + (float)gic) / (float)NWW;
            float py = (vy + (float)gjc) / (float)NHH;
            float dx = (tg[1 + 2 * k] - px) * IMW_;
            float dy = (tg[2 + 2 * k] - py) * IMH_;
            float dn = sqrtf(dx * dx + dy * dy);
            if (dn < TH_) ssum += expf(SHARP_ * (1.0f - dn / TH_)) - 1.0f;
        }
        conf_t_ws[b * NT + t] = (ssum / 9.0f) / denom;

        // tvals (uses raw gi/gj as floats, per reference)
        float* tv = tvals_ws + (size_t)(b * NT + t) * 18;
        for (int k = 0; k < 9; ++k) {
            tv[2 * k]     = tg[1 + 2 * k] * (float)NWW - (float)gi;
            tv[2 * k + 1] = tg[2 + 2 * k] * (float)NHH - (float)gj;
        }
    }
    __syncthreads();

    // Winner resolution: last valid in-bounds target per cell wins (JAX/np scatter order).
    if (t < NT) {
        int gi = sgi[t], gj = sgj[t];
        if (svalid[t] && gi >= 0 && gi < NWW && gj >= 0 && gj < NHH) {
            bool win = true;
            for (int k2 = t + 1; k2 < NT; ++k2) {
                if (svalid[k2] && sgi[k2] == gi && sgj[k2] == gj) { win = false; break; }
            }
            if (win) cellmap[b * CELLS + gj * NWW + gi] = t;
        }
    }
}

__global__ void loss_kernel(const float* __restrict__ outp,
                            const int* __restrict__ cellmap,
                            const float* __restrict__ conf_t_ws,
                            const float* __restrict__ tvals_ws,
                            double* __restrict__ partials) {
    int idx = blockIdx.x * 256 + threadIdx.x;
    double acc = 0.0;
    if (idx < TOTAL) {
        int cell = idx % CELLS;
        int ba = idx / CELLS;   // b*NA + a
        int a = ba % NA;
        int b = ba / NA;
        const float* base = outp + (size_t)ba * CH * CELLS;
        float conf = sigmoidf_(base[(size_t)18 * CELLS + cell]);

        int m = -1;
        if (a == 0) m = cellmap[b * CELLS + cell];

        if (m >= 0) {
            // obj cell: conf term with OBJ scale + coord term
            float tc = conf_t_ws[b * NT + m];
            float dc = conf - tc;
            acc += 0.5 * (double)(OBJ_SCALE * dc * dc);
            const float* tv = tvals_ws + (size_t)(b * NT + m) * 18;
            float s = 0.0f;
            for (int c = 0; c < 18; ++c) {
                float v = base[(size_t)c * CELLS + cell];
                if (c < 2) v = sigmoidf_(v);
                float d = v - tv[c];
                s += d * d;
            }
            acc += 0.5 * (double)(COORD_SCALE * s);
        } else {
            acc += 0.5 * (double)(conf * conf);  // noobj: scale 1, tconf 0
        }
    }

    __shared__ double sdata[256];
    sdata[threadIdx.x] = acc;
    __syncthreads();
    for (int s = 128; s > 0; s >>= 1) {
        if (threadIdx.x < s) sdata[threadIdx.x] += sdata[threadIdx.x + s];
        __syncthreads();
    }
    if (threadIdx.x == 0) partials[blockIdx.x] = sdata[0];
}

__global__ void final_kernel(const double* __restrict__ partials, int n,
                             float* __restrict__ out) {
    __shared__ double sdata[256];
    double acc = 0.0;
    for (int i = threadIdx.x; i < n; i += 256) acc += partials[i];
    sdata[threadIdx.x] = acc;
    __syncthreads();
    for (int s = 128; s > 0; s >>= 1) {
        if (threadIdx.x < s) sdata[threadIdx.x] += sdata[threadIdx.x + s];
        __syncthreads();
    }
    if (threadIdx.x == 0) out[0] = (float)sdata[0];
}

extern "C" void kernel_launch(void* const* d_in, const int* in_sizes, int n_in,
                              void* d_out, int out_size, void* d_ws, size_t ws_size,
                              hipStream_t stream) {
    const float* outp = (const float*)d_in[0];
    const float* tgt  = (const float*)d_in[1];
    float* out = (float*)d_out;
    char* ws = (char*)d_ws;

    int*    cellmap   = (int*)ws;
    float*  conf_t_ws = (float*)(ws + WS_CONF_T_OFF);
    float*  tvals_ws  = (float*)(ws + WS_TVALS_OFF);
    double* partials  = (double*)(ws + WS_PART_OFF);

    // re-init cellmap each call (harness does not re-poison ws between replays)
    hipMemsetAsync(cellmap, 0xFF, (size_t)NB * CELLS * sizeof(int), stream);

    targets_kernel<<<NB, 64, 0, stream>>>(outp, tgt, cellmap, conf_t_ws, tvals_ws);
    loss_kernel<<<MAIN_BLOCKS, 256, 0, stream>>>(outp, cellmap, conf_t_ws, tvals_ws, partials);
    final_kernel<<<1, 256, 0, stream>>>(partials, MAIN_BLOCKS, out);
}